// Round 13
// baseline (1592.614 us; speedup 1.0000x reference)
//
#include <hip/hip_runtime.h>
#include <cstdint>

typedef unsigned short u16;
typedef __attribute__((ext_vector_type(8))) short bf16x8;   // 8 bf16 (4 VGPRs)
typedef __attribute__((ext_vector_type(4))) float f32x4;
typedef __attribute__((ext_vector_type(4))) unsigned short u16x4;

__device__ __forceinline__ u16 f2b(float f) {  // fp32 -> bf16 RNE
  union { float f; uint32_t u; } v; v.f = f;
  uint32_t r = v.u + 0x7FFFu + ((v.u >> 16) & 1u);
  return (u16)(r >> 16);
}

__device__ __forceinline__ void gload_lds16(const void* g, void* l) {
  __builtin_amdgcn_global_load_lds((const __attribute__((address_space(1))) void*)g,
                                   (__attribute__((address_space(3))) void*)l, 16, 0, 0);
}

__device__ __forceinline__ void barrier_raw() {
  __builtin_amdgcn_sched_barrier(0);
  asm volatile("" ::: "memory");
  __builtin_amdgcn_s_barrier();
  asm volatile("" ::: "memory");
  __builtin_amdgcn_sched_barrier(0);
}
__device__ __forceinline__ void wait_vm4() {
  asm volatile("s_waitcnt vmcnt(4)" ::: "memory");
  __builtin_amdgcn_sched_barrier(0);
}
__device__ __forceinline__ void wait_lgkm0() {
  asm volatile("s_waitcnt lgkmcnt(0)" ::: "memory");
  __builtin_amdgcn_sched_barrier(0);
}

// ---------------- elementwise fp32 -> bf16 ----------------
__global__ __launch_bounds__(256) void cvt_bf16(const float* __restrict__ in,
                                                u16* __restrict__ out, long n) {
  long i = ((long)blockIdx.x * 256 + threadIdx.x) * 4;
  if (i >= n) return;
  f32x4 v = *(const f32x4*)(in + i);
  u16x4 o;
#pragma unroll
  for (int k = 0; k < 4; k++) o[k] = f2b(v[k]);
  *(u16x4*)(out + i) = o;
}

// ---------------- W (K,N) fp32 -> WT (N,K) bf16, 32x32 LDS tiles ----------------
__global__ __launch_bounds__(256) void transpose_cvt(const float* __restrict__ W,
                                                     u16* __restrict__ WT, int K, int N) {
  __shared__ float tile[32][33];
  const int tn0 = blockIdx.x * 32;
  const int tk0 = blockIdx.y * 32;
  const int c = threadIdx.x & 31;
  const int r0 = threadIdx.x >> 5;
#pragma unroll
  for (int rr = 0; rr < 32; rr += 8)
    tile[r0 + rr][c] = W[(long)(tk0 + r0 + rr) * N + tn0 + c];
  __syncthreads();
#pragma unroll
  for (int rr = 0; rr < 32; rr += 8)
    WT[(long)(tn0 + r0 + rr) * K + tk0 + c] = f2b(tile[c][r0 + rr]);
}

// ---------------- concat biases ----------------
__global__ __launch_bounds__(256) void biascat3(const float* __restrict__ a,
                                                const float* __restrict__ b,
                                                const float* __restrict__ c,
                                                float* __restrict__ o) {
  int i = blockIdx.x * 256 + threadIdx.x;
  if (i < 1536) o[i] = a[i];
  else if (i < 2048) o[i] = b[i - 1536];
  else if (i < 2112) o[i] = c[i - 2048];
}
__global__ __launch_bounds__(256) void biascat2(const float* __restrict__ a,
                                                const float* __restrict__ b,
                                                int na, int n, float* __restrict__ o) {
  int i = blockIdx.x * 256 + threadIdx.x;
  if (i >= n) return;
  o[i] = (i < na) ? a[i] : b[i - na];
}

// ---------------- replicate K_r (4096,64 in strided lat buffer) into Kbuf ----------------
__global__ __launch_bounds__(256) void repl_kr(const u16* __restrict__ Kr,
                                               u16* __restrict__ Kbuf, int stride) {
  long idx = (long)blockIdx.x * 256 + threadIdx.x;   // (tok, h, d4)
  int d4 = idx & 15;
  long t = idx >> 4;
  int hh = t & 63;
  long tok = t >> 6;
  if (tok >= 4096) return;
  u16x4 v = *(const u16x4*)(Kr + tok * (long)stride + d4 * 4);
  long b = tok >> 10, l = tok & 1023;
  *(u16x4*)(Kbuf + ((b * 64 + hh) * 1024 + l) * 192 + 128 + d4 * 4) = v;
}

// ---------------- 256x256 quadrant-phased bf16 GEMM (m201 structure) ----------------
// 4 phases/K-tile, each = one 64x32-quadrant x K=64 (16 MFMA). A-frags held 2 phases,
// BOTH B-frag sets held whole tile (reads/phase: 12/4/8/0). One vmcnt(4) per tile at ph4
// (ledger: forces exactly tile-t+1's 4 halves, floats kh0(t+2) — never drains).
// Stage placement vs last reader: A.kh1(t+1)->nxt@ph1, B.kh1(t+1)->nxt@ph2,
// B.kh0(t+2)->cur@ph3 (B last read ph2), A.kh0(t+2)->cur@ph4 (A last read ph3).
// Chunk-XOR swizzle both-sides (0 bank conflicts, R5-verified).
// MODE 0: bf16 (M,N)   MODE 3: fp32 (M,N)   MODE 4: fused Q   MODE 5: fused KV
template<int MODE>
__global__ __launch_bounds__(512, 2) void gemm256(
    const u16* __restrict__ A, long lda, const u16* __restrict__ BT, long ldb,
    const float* __restrict__ bias, void* __restrict__ outp, void* __restrict__ outp2,
    int N, int K) {
  __shared__ u16 sA[2][2][8192];
  __shared__ u16 sB[2][2][8192];
  const int tid = threadIdx.x;
  const int lane = tid & 63;
  const int w = tid >> 6;
  const int wr = w >> 2, wc = w & 3;
  const int hi = lane >> 4, lo = lane & 15;

  // ---- XCD-aware 2D rectangle scheduling ----
  const int Nt = gridDim.x, Mt = gridDim.y;
  const int bid = blockIdx.y * Nt + blockIdx.x;
  const int xcd = bid & 7;
  const int idx = bid >> 3;
  int mt, nt;
  if ((Nt & 1) == 0) {
    const int Rm = Mt >> 2, Rn = Nt >> 1;
    const int xr = xcd & 3, xcn = xcd >> 2;
    const int Wb = Rn < 8 ? Rn : 8;
    const int cb = idx / (Rm * Wb);
    const int rem = idx - cb * (Rm * Wb);
    mt = xr * Rm + (rem % Rm);
    nt = xcn * Rn + cb * Wb + rem / Rm;
  } else {
    const int Rm = Mt >> 3;
    const int Wb = Nt < 8 ? Nt : 8;
    const int cb = idx / (Rm * Wb);
    const int rem = idx - cb * (Rm * Wb);
    mt = xcd * Rm + (rem % Rm);
    nt = cb * Wb + rem / Rm;
  }
  const long m0 = (long)mt * 256;
  const long n0 = (long)nt * 256;

  const int nkt = K >> 6;

  const int srow = tid >> 2;
  const int scol = ((tid & 3) ^ ((tid >> 3) & 3)) * 8;
  const long arow0 = m0 + srow, arow1 = arow0 + 128;
  long brow0 = n0 + srow, brow1 = brow0 + 128;
  if (brow0 > N - 1) brow0 = N - 1;
  if (brow1 > N - 1) brow1 = N - 1;
  const u16* aS0 = A + arow0 * lda + scol;
  const u16* aS1 = A + arow1 * lda + scol;
  const u16* bS0 = BT + brow0 * ldb + scol;
  const u16* bS1 = BT + brow1 * ldb + scol;

  const int aRd = (wr * 128 + lo) * 32 + (hi ^ ((lo >> 1) & 3)) * 8;
  const int bRd = (wc * 64 + lo) * 32 + (hi ^ ((lo >> 1) & 3)) * 8;

  f32x4 acc[8][4] = {};

#define STAGE(s0, s1, koff, dst) do { \
    gload_lds16((s0) + (koff), (dst) + tid * 8); \
    gload_lds16((s1) + (koff), (dst) + 4096 + tid * 8); \
  } while (0)
#define LD_A(kst, m) (*(const bf16x8*)(&sA[cur][kst][aRd + (m) * 512]))
#define LD_B(kst, n) (*(const bf16x8*)(&sB[cur][kst][bRd + (n) * 512]))
#define MF(d, av, bv) d = __builtin_amdgcn_mfma_f32_16x16x32_bf16(av, bv, d, 0, 0, 0)
#define QUAD(R0, C0, B00, B01, B10, B11) \
    MF(acc[R0+0][C0+0], a00, B00); MF(acc[R0+0][C0+0], a01, B01); \
    MF(acc[R0+0][C0+1], a00, B10); MF(acc[R0+0][C0+1], a01, B11); \
    MF(acc[R0+1][C0+0], a10, B00); MF(acc[R0+1][C0+0], a11, B01); \
    MF(acc[R0+1][C0+1], a10, B10); MF(acc[R0+1][C0+1], a11, B11); \
    MF(acc[R0+2][C0+0], a20, B00); MF(acc[R0+2][C0+0], a21, B01); \
    MF(acc[R0+2][C0+1], a20, B10); MF(acc[R0+2][C0+1], a21, B11); \
    MF(acc[R0+3][C0+0], a30, B00); MF(acc[R0+3][C0+0], a31, B01); \
    MF(acc[R0+3][C0+1], a30, B10); MF(acc[R0+3][C0+1], a31, B11);

  // prologue: tile0 (4 halves) + tile1 kh0 {B, A}; vmcnt(4) forces tile0, floats 4.
  STAGE(aS0, aS1, 0, &sA[0][0][0]);
  STAGE(bS0, bS1, 0, &sB[0][0][0]);
  STAGE(aS0, aS1, 32, &sA[0][1][0]);
  STAGE(bS0, bS1, 32, &sB[0][1][0]);
  {
    const long t1o = (nkt > 1) ? 64 : 0;
    STAGE(bS0, bS1, t1o, &sB[1][0][0]);
    STAGE(aS0, aS1, t1o, &sA[1][0][0]);
  }
  wait_vm4();
  barrier_raw();

  for (int t = 0; t < nkt; ++t) {
    const int cur = t & 1, nxt = cur ^ 1;
    const int t1c = (t + 1 < nkt) ? t + 1 : nkt - 1;
    const int t2c = (t + 2 < nkt) ? t + 2 : nkt - 1;
    const long o1 = (long)t1c * 64;
    const long o2 = (long)t2c * 64;
    bf16x8 a00, a01, a10, a11, a20, a21, a30, a31;
    bf16x8 b000, b001, b010, b011;   // B cols 0,1 (held whole tile)
    bf16x8 b100, b101, b110, b111;   // B cols 2,3 (held ph2..ph3)
    // ---- phase 1: quadrant (m0-3, n0-1); 12 reads; stage A.kh1(t+1)->nxt ----
    a00 = LD_A(0, 0); a01 = LD_A(1, 0); a10 = LD_A(0, 1); a11 = LD_A(1, 1);
    a20 = LD_A(0, 2); a21 = LD_A(1, 2); a30 = LD_A(0, 3); a31 = LD_A(1, 3);
    b000 = LD_B(0, 0); b001 = LD_B(1, 0); b010 = LD_B(0, 1); b011 = LD_B(1, 1);
    STAGE(aS0, aS1, o1 + 32, &sA[nxt][1][0]);
    barrier_raw();
    wait_lgkm0();
    __builtin_amdgcn_s_setprio(1);
    QUAD(0, 0, b000, b001, b010, b011)
    __builtin_amdgcn_s_setprio(0);
    barrier_raw();
    // ---- phase 2: quadrant (m0-3, n2-3); 4 reads; stage B.kh1(t+1)->nxt ----
    b100 = LD_B(0, 2); b101 = LD_B(1, 2); b110 = LD_B(0, 3); b111 = LD_B(1, 3);
    STAGE(bS0, bS1, o1 + 32, &sB[nxt][1][0]);
    barrier_raw();
    wait_lgkm0();
    __builtin_amdgcn_s_setprio(1);
    QUAD(0, 2, b100, b101, b110, b111)
    __builtin_amdgcn_s_setprio(0);
    barrier_raw();
    // ---- phase 3: quadrant (m4-7, n2-3); 8 reads; stage B.kh0(t+2)->cur (B last read ph2) ----
    a00 = LD_A(0, 4); a01 = LD_A(1, 4); a10 = LD_A(0, 5); a11 = LD_A(1, 5);
    a20 = LD_A(0, 6); a21 = LD_A(1, 6); a30 = LD_A(0, 7); a31 = LD_A(1, 7);
    STAGE(bS0, bS1, o2, &sB[cur][0][0]);
    barrier_raw();
    wait_lgkm0();
    __builtin_amdgcn_s_setprio(1);
    QUAD(4, 2, b100, b101, b110, b111)
    __builtin_amdgcn_s_setprio(0);
    barrier_raw();
    // ---- phase 4: quadrant (m4-7, n0-1); 0 reads; stage A.kh0(t+2)->cur (A last read ph3) ----
    STAGE(aS0, aS1, o2, &sA[cur][0][0]);
    __builtin_amdgcn_s_setprio(1);
    QUAD(4, 0, b000, b001, b010, b011)
    __builtin_amdgcn_s_setprio(0);
    wait_vm4();
    barrier_raw();
  }
  asm volatile("s_waitcnt vmcnt(0)" ::: "memory");

#undef STAGE
#undef LD_A
#undef LD_B
#undef MF
#undef QUAD

#pragma unroll
  for (int m = 0; m < 8; m++) {
#pragma unroll
    for (int n = 0; n < 4; n++) {
      const long mb = m0 + wr * 128 + m * 16 + hi * 4;
      const long nn = n0 + wc * 64 + n * 16 + lo;
      if (nn >= N) continue;
      const float bv = bias[nn];
      if (MODE == 0) {
#pragma unroll
        for (int r = 0; r < 4; r++)
          ((u16*)outp)[(mb + r) * (long)N + nn] = f2b(acc[m][n][r] + bv);
      } else if (MODE == 3) {
#pragma unroll
        for (int r = 0; r < 4; r++)
          ((float*)outp)[(mb + r) * (long)N + nn] = acc[m][n][r] + bv;
      } else if (MODE == 4) {
        if (nn < 8192) {
          const long h = nn >> 7, d = nn & 127;
#pragma unroll
          for (int r = 0; r < 4; r++) {
            const long mm = mb + r;
            const long bq = mm >> 10, l = mm & 1023;
            ((u16*)outp)[((bq * 64 + h) * 1024 + l) * 192 + d] = f2b(acc[m][n][r] + bv);
          }
        } else {
          const long q = nn - 8192;
          const long h = q >> 6, d = q & 63;
#pragma unroll
          for (int r = 0; r < 4; r++) {
            const long mm = mb + r;
            const long bq = mm >> 10, l = mm & 1023;
            ((u16*)outp)[((bq * 64 + h) * 1024 + l) * 192 + 128 + d] = f2b(acc[m][n][r] + bv);
          }
        }
      } else {                      // MODE 5
        if (nn < 8192) {
          const long h = nn >> 7, d = nn & 127;
#pragma unroll
          for (int r = 0; r < 4; r++) {
            const long mm = mb + r;
            const long bq = mm >> 10, l = mm & 1023;
            ((u16*)outp)[((bq * 64 + h) * 1024 + l) * 192 + d] = f2b(acc[m][n][r] + bv);
          }
        } else {
          const long v = nn - 8192;
          const long h = v >> 7, d = v & 127;
          u16x4 pk;
#pragma unroll
          for (int r = 0; r < 4; r++) pk[r] = f2b(acc[m][n][r] + bv);
          const long bq = mb >> 10, l = mb & 1023;
          *(u16x4*)((u16*)outp2 + ((bq * 64 + h) * 128 + d) * 1024 + l) = pk;
        }
      }
    }
  }
}

// ---------------- causal flash attention, 8-wave 256-row q-tile, LDS-staged K/V ----------------
__global__ __launch_bounds__(512, 2) void attn256(const u16* __restrict__ Qb,
                                                  const u16* __restrict__ Kb,
                                                  const u16* __restrict__ Vt,
                                                  u16* __restrict__ O) {
  __shared__ u16 sK[2][12288];
  __shared__ u16 sV[2][8192];
  __shared__ u16 P[8][32][72];
  const int bh = blockIdx.x;
  const int qtb = 3 - blockIdx.y;
  const int b = bh >> 6, h = bh & 63;
  const int tid = threadIdx.x, w = tid >> 6, lane = tid & 63;
  const int hi = lane >> 4, lo = lane & 15, lo7 = lane & 7;
  const int q0w = qtb * 256 + w * 32;
  const u16* Qh = Qb + (size_t)bh * 1024 * 192;
  const u16* Kh = Kb + (size_t)bh * 1024 * 192;
  const u16* Vh = Vt + (size_t)bh * 128 * 1024;
  const float scale = 0.08838834764831845f;
  const float NEGINF = -3.0e38f;

  int kOff0, kOff1, kOff2, vOff0, vOff1;
  {
    int g0 = tid, g1 = tid + 512, g2 = tid + 1024;
    int r0 = g0 / 24, r1 = g1 / 24, r2 = g2 / 24;
    kOff0 = r0 * 192 + ((g0 - r0 * 24) ^ (r0 & 7)) * 8;
    kOff1 = r1 * 192 + ((g1 - r1 * 24) ^ (r1 & 7)) * 8;
    kOff2 = r2 * 192 + ((g2 - r2 * 24) ^ (r2 & 7)) * 8;
    int s0 = tid, s1 = tid + 512;
    vOff0 = (s0 >> 3) * 1024 + ((s0 & 7) ^ ((s0 >> 3) & 7)) * 8;
    vOff1 = (s1 >> 3) * 1024 + ((s1 & 7) ^ ((s1 >> 3) & 7)) * 8;
  }
#define STAGE_KV(tt, bb) do { \
    const u16* kb_ = Kh + (size_t)(tt) * (64 * 192); \
    const u16* vb_ = Vh + (size_t)(tt) * 64; \
    gload_lds16(kb_ + kOff0, &sK[bb][0] + tid * 8); \
    gload_lds16(kb_ + kOff1, &sK[bb][4096] + tid * 8); \
    gload_lds16(kb_ + kOff2, &sK[bb][8192] + tid * 8); \
    gload_lds16(vb_ + vOff0, &sV[bb][0] + tid * 8); \
    gload_lds16(vb_ + vOff1, &sV[bb][4096] + tid * 8); \
  } while (0)

  bf16x8 qf[2][6];
#pragma unroll
  for (int qi = 0; qi < 2; qi++) {
    const u16* qp = Qh + (size_t)(q0w + qi * 16 + lo) * 192 + hi * 8;
#pragma unroll
    for (int f = 0; f < 6; f++) qf[qi][f] = *(const bf16x8*)(qp + f * 32);
  }

  f32x4 oacc[2][8] = {};
  float m_run[2][4], l_run[2][4];
#pragma unroll
  for (int qi = 0; qi < 2; qi++)
#pragma unroll
    for (int r = 0; r < 4; r++) { m_run[qi][r] = NEGINF; l_run[qi][r] = 0.f; }

  const int nkt = (qtb + 1) * 4;
  STAGE_KV(0, 0);
  __syncthreads();

  for (int t = 0; t < nkt; t++) {
    const int cur = t & 1;
    const int tn = (t + 1 < nkt) ? t + 1 : nkt - 1;
    STAGE_KV(tn, cur ^ 1);
    const int k0 = t * 64;
    if (k0 < q0w + 32) {
      f32x4 s[2][4] = {};
      __builtin_amdgcn_s_setprio(1);
#pragma unroll
      for (int j = 0; j < 4; j++) {
#pragma unroll
        for (int f = 0; f < 6; f++) {
          bf16x8 kf = *(const bf16x8*)(&sK[cur][((j * 16 + lo) * 24 + ((f * 4 + hi) ^ lo7)) * 8]);
          s[0][j] = __builtin_amdgcn_mfma_f32_16x16x32_bf16(qf[0][f], kf, s[0][j], 0, 0, 0);
          s[1][j] = __builtin_amdgcn_mfma_f32_16x16x32_bf16(qf[1][f], kf, s[1][j], 0, 0, 0);
        }
      }
      __builtin_amdgcn_s_setprio(0);
      const bool diag = (k0 + 63 > q0w);
#pragma unroll
      for (int qi = 0; qi < 2; qi++) {
#pragma unroll
        for (int r = 0; r < 4; r++) {
          const int q = q0w + qi * 16 + hi * 4 + r;
          float sv[4];
          float mx = NEGINF;
#pragma unroll
          for (int j = 0; j < 4; j++) {
            float v = s[qi][j][r] * scale;
            if (diag && (k0 + j * 16 + lo > q)) v = NEGINF;
            sv[j] = v;
            mx = fmaxf(mx, v);
          }
#pragma unroll
          for (int o = 1; o < 16; o <<= 1) mx = fmaxf(mx, __shfl_xor(mx, o, 64));
          const float mnew = fmaxf(m_run[qi][r], mx);
          float sum = 0.f;
#pragma unroll
          for (int j = 0; j < 4; j++) {
            float pv = __expf(sv[j] - mnew);
            sum += pv;
            P[w][qi * 16 + hi * 4 + r][j * 16 + lo] = f2b(pv);
          }
#pragma unroll
          for (int o = 1; o < 16; o <<= 1) sum += __shfl_xor(sum, o, 64);
          const float alpha = __expf(m_run[qi][r] - mnew);
          l_run[qi][r] = l_run[qi][r] * alpha + sum;
          m_run[qi][r] = mnew;
#pragma unroll
          for (int j = 0; j < 8; j++) oacc[qi][j][r] *= alpha;
        }
      }
      __builtin_amdgcn_s_setprio(1);
#pragma unroll
      for (int kk = 0; kk < 2; kk++) {
        bf16x8 pf0 = *(const bf16x8*)(&P[w][lo][kk * 32 + hi * 8]);
        bf16x8 pf1 = *(const bf16x8*)(&P[w][16 + lo][kk * 32 + hi * 8]);
#pragma unroll
        for (int j = 0; j < 8; j++) {
          bf16x8 vf = *(const bf16x8*)(&sV[cur][((j * 16 + lo) * 8 + ((kk * 4 + hi) ^ lo7)) * 8]);
          oacc[0][j] = __builtin_amdgcn_mfma_f32_16x16x32_bf16(pf0, vf, oacc[0][j], 0, 0, 0);
          oacc[1][j] = __builtin_amdgcn_mfma_f32_16x16x32_bf16(pf1, vf, oacc[1][j], 0, 0, 0);
        }
      }
      __builtin_amdgcn_s_setprio(0);
    }
    __syncthreads();
  }
#undef STAGE_KV

#pragma unroll
  for (int qi = 0; qi < 2; qi++) {
#pragma unroll
    for (int r = 0; r < 4; r++) {
      const float inv = 1.f / l_run[qi][r];
      const int q = q0w + qi * 16 + hi * 4 + r;
      u16* op = O + ((size_t)(b * 1024 + q) * 64 + h) * 128;
#pragma unroll
      for (int j = 0; j < 8; j++)
        op[j * 16 + lo] = f2b(oacc[qi][j][r] * inv);
    }
  }
}

// ---------------- launcher ----------------
extern "C" void kernel_launch(void* const* d_in, const int* in_sizes, int n_in,
                              void* d_out, int out_size, void* d_ws, size_t ws_size,
                              hipStream_t stream) {
  const float* x     = (const float*)d_in[0];
  const float* W_dq  = (const float*)d_in[1];
  const float* b_dq  = (const float*)d_in[2];
  const float* W_dkv = (const float*)d_in[3];
  const float* b_dkv = (const float*)d_in[4];
  const float* W_uq  = (const float*)d_in[5];
  const float* b_uq  = (const float*)d_in[6];
  const float* W_uk  = (const float*)d_in[7];
  const float* b_uk  = (const float*)d_in[8];
  const float* W_uv  = (const float*)d_in[9];
  const float* b_uv  = (const float*)d_in[10];
  const float* W_pq  = (const float*)d_in[11];
  const float* b_pq  = (const float*)d_in[12];
  const float* W_pk  = (const float*)d_in[13];
  const float* b_pk  = (const float*)d_in[14];
  const float* W_o   = (const float*)d_in[15];
  const float* b_o   = (const float*)d_in[16];

  char* ws = (char*)d_ws;
  size_t off = 0;
  auto alloc = [&](size_t bytes) {
    char* p = ws + off;
    off += (bytes + 255) & ~(size_t)255;
    return p;
  };
  u16* xbf   = (u16*)alloc(33554432ULL * 2);   // x bf16; reused as attn O
  u16* WT    = (u16*)alloc(67108864ULL * 2);   // transposed-weight scratch (max = W_o)
  u16* lat   = (u16*)alloc(4096ULL * 2112 * 2);// [Q_lat | KV_lat | K_r]
  float* bct = (float*)alloc(2112ULL * 4);
  float* bq  = (float*)alloc(12288ULL * 4);
  float* bkv = (float*)alloc(16384ULL * 4);
  u16* Qbuf  = (u16*)alloc(100663296ULL);      // (B,NH,L,192)
  u16* Kbuf  = (u16*)alloc(100663296ULL);      // (B,NH,L,192)
  u16* Vt    = (u16*)alloc(67108864ULL);       // (B,NH,128,L)
  u16* Obuf  = xbf;
  if (off > ws_size) return;

  dim3 blk(256), blk5(512);
  cvt_bf16<<<dim3(32768), blk, 0, stream>>>(x, xbf, 33554432L);
  // fused latent: [Q_lat | KV_lat | K_r] = x @ [W_dq | W_dkv | W_pk] + biases
  transpose_cvt<<<dim3(48, 256), blk, 0, stream>>>(W_dq, WT, 8192, 1536);
  transpose_cvt<<<dim3(16, 256), blk, 0, stream>>>(W_dkv, WT + 1536L * 8192, 8192, 512);
  transpose_cvt<<<dim3(2, 256), blk, 0, stream>>>(W_pk, WT + 2048L * 8192, 8192, 64);
  biascat3<<<dim3(9), blk, 0, stream>>>(b_dq, b_dkv, b_pk, bct);
  gemm256<0><<<dim3(9, 16), blk5, 0, stream>>>(xbf, 8192, WT, 8192, bct, lat, nullptr, 2112, 8192);
  repl_kr<<<dim3(16384), blk, 0, stream>>>(lat + 2048, Kbuf, 2112);
  // fused Q: [Q_c | Q_r] = Q_lat @ [W_uq | W_pq], N = 12288
  transpose_cvt<<<dim3(256, 48), blk, 0, stream>>>(W_uq, WT, 1536, 8192);
  transpose_cvt<<<dim3(128, 48), blk, 0, stream>>>(W_pq, WT + 8192L * 1536, 1536, 4096);
  biascat2<<<dim3(48), blk, 0, stream>>>(b_uq, b_pq, 8192, 12288, bq);
  gemm256<4><<<dim3(48, 16), blk5, 0, stream>>>(lat, 2112, WT, 1536, bq, Qbuf, nullptr, 12288, 1536);
  // fused KV: [K_c | V] = KV_lat @ [W_uk | W_uv], N = 16384
  transpose_cvt<<<dim3(256, 16), blk, 0, stream>>>(W_uk, WT, 512, 8192);
  transpose_cvt<<<dim3(256, 16), blk, 0, stream>>>(W_uv, WT + 8192L * 512, 512, 8192);
  biascat2<<<dim3(64), blk, 0, stream>>>(b_uk, b_uv, 8192, 16384, bkv);
  gemm256<5><<<dim3(64, 16), blk5, 0, stream>>>(lat + 1536, 2112, WT, 512, bkv, Kbuf, Vt, 16384, 512);
  // attention (8-wave, 256-row q-tiles, LDS-staged K/V)
  attn256<<<dim3(256, 4), blk5, 0, stream>>>(Qbuf, Kbuf, Vt, Obuf);
  // out = O @ W_o + b_o (fp32)
  transpose_cvt<<<dim3(256, 256), blk, 0, stream>>>(W_o, WT, 8192, 8192);
  gemm256<3><<<dim3(32, 16), blk5, 0, stream>>>(Obuf, 8192, WT, 8192, b_o, d_out, nullptr, 8192, 8192);
}

// Round 14
// 1380.501 us; speedup vs baseline: 1.1536x; 1.1536x over previous
//
#include <hip/hip_runtime.h>
#include <cstdint>

typedef unsigned short u16;
typedef __attribute__((ext_vector_type(8))) short bf16x8;   // 8 bf16 (4 VGPRs)
typedef __attribute__((ext_vector_type(4))) float f32x4;
typedef __attribute__((ext_vector_type(4))) unsigned short u16x4;

__device__ __forceinline__ u16 f2b(float f) {  // fp32 -> bf16 RNE
  union { float f; uint32_t u; } v; v.f = f;
  uint32_t r = v.u + 0x7FFFu + ((v.u >> 16) & 1u);
  return (u16)(r >> 16);
}

__device__ __forceinline__ void gload_lds16(const void* g, void* l) {
  __builtin_amdgcn_global_load_lds((const __attribute__((address_space(1))) void*)g,
                                   (__attribute__((address_space(3))) void*)l, 16, 0, 0);
}

__device__ __forceinline__ void barrier_raw() {
  __builtin_amdgcn_sched_barrier(0);
  asm volatile("" ::: "memory");
  __builtin_amdgcn_s_barrier();
  asm volatile("" ::: "memory");
  __builtin_amdgcn_sched_barrier(0);
}
__device__ __forceinline__ void wait_vm8() {
  asm volatile("s_waitcnt vmcnt(8)" ::: "memory");
  __builtin_amdgcn_sched_barrier(0);
}

// ---------------- elementwise fp32 -> bf16 ----------------
__global__ __launch_bounds__(256) void cvt_bf16(const float* __restrict__ in,
                                                u16* __restrict__ out, long n) {
  long i = ((long)blockIdx.x * 256 + threadIdx.x) * 4;
  if (i >= n) return;
  f32x4 v = *(const f32x4*)(in + i);
  u16x4 o;
#pragma unroll
  for (int k = 0; k < 4; k++) o[k] = f2b(v[k]);
  *(u16x4*)(out + i) = o;
}

// ---------------- W (K,N) fp32 -> WT (N,K) bf16, 32x32 LDS tiles ----------------
__global__ __launch_bounds__(256) void transpose_cvt(const float* __restrict__ W,
                                                     u16* __restrict__ WT, int K, int N) {
  __shared__ float tile[32][33];
  const int tn0 = blockIdx.x * 32;
  const int tk0 = blockIdx.y * 32;
  const int c = threadIdx.x & 31;
  const int r0 = threadIdx.x >> 5;
#pragma unroll
  for (int rr = 0; rr < 32; rr += 8)
    tile[r0 + rr][c] = W[(long)(tk0 + r0 + rr) * N + tn0 + c];
  __syncthreads();
#pragma unroll
  for (int rr = 0; rr < 32; rr += 8)
    WT[(long)(tn0 + r0 + rr) * K + tk0 + c] = f2b(tile[c][r0 + rr]);
}

// ---------------- concat biases ----------------
__global__ __launch_bounds__(256) void biascat3(const float* __restrict__ a,
                                                const float* __restrict__ b,
                                                const float* __restrict__ c,
                                                float* __restrict__ o) {
  int i = blockIdx.x * 256 + threadIdx.x;
  if (i < 1536) o[i] = a[i];
  else if (i < 2048) o[i] = b[i - 1536];
  else if (i < 2112) o[i] = c[i - 2048];
}
__global__ __launch_bounds__(256) void biascat2(const float* __restrict__ a,
                                                const float* __restrict__ b,
                                                int na, int n, float* __restrict__ o) {
  int i = blockIdx.x * 256 + threadIdx.x;
  if (i >= n) return;
  o[i] = (i < na) ? a[i] : b[i - na];
}

// ---------------- replicate K_r (4096,64 in strided lat buffer) into Kbuf ----------------
__global__ __launch_bounds__(256) void repl_kr(const u16* __restrict__ Kr,
                                               u16* __restrict__ Kbuf, int stride) {
  long idx = (long)blockIdx.x * 256 + threadIdx.x;   // (tok, h, d4)
  int d4 = idx & 15;
  long t = idx >> 4;
  int hh = t & 63;
  long tok = t >> 6;
  if (tok >= 4096) return;
  u16x4 v = *(const u16x4*)(Kr + tok * (long)stride + d4 * 4);
  long b = tok >> 10, l = tok & 1023;
  *(u16x4*)(Kbuf + ((b * 64 + hh) * 1024 + l) * 192 + 128 + d4 * 4) = v;
}

// ---------------- 256x256 pipelined bf16 GEMM (R6 schedule: 2 half-phases, 4 barriers) ----------------
// Per tile: each half issues all 12 frag reads pre-barrier; A-half staged pre-barrier,
// B-half staged INSIDE the MFMA cluster; vmcnt(8) twice per tile keeps exactly the last
// 4 half-stages floating (consumed halves forced >= 1 full tile after issue).
// Chunk-XOR swizzle both-sides (R5: 0 bank conflicts).
// MODE 0: bf16 (M,N) row-major (N-guarded; B rows clamped)
// MODE 3: fp32 (M,N)
// MODE 4: fused Q epilogue: nn<8192 -> Q_c head layout; else Q_r (d+128)
// MODE 5: fused KV epilogue: nn<8192 -> K_c head layout (outp); else V-transpose (outp2)
template<int MODE>
__global__ __launch_bounds__(512, 2) void gemm256(
    const u16* __restrict__ A, long lda, const u16* __restrict__ BT,
    const float* __restrict__ bias, void* __restrict__ outp, void* __restrict__ outp2,
    int N, int K) {
  __shared__ u16 sA[2][2][8192];
  __shared__ u16 sB[2][2][8192];
  const int tid = threadIdx.x;
  const int lane = tid & 63;
  const int w = tid >> 6;
  const int wr = w >> 2, wc = w & 3;
  const int hi = lane >> 4, lo = lane & 15;

  // ---- XCD-aware 2D rectangle scheduling ----
  const int Nt = gridDim.x, Mt = gridDim.y;
  const int bid = blockIdx.y * Nt + blockIdx.x;
  const int xcd = bid & 7;
  const int idx = bid >> 3;
  int mt, nt;
  if ((Nt & 1) == 0) {                      // Mt%4==0, Nt%2==0 path
    const int Rm = Mt >> 2, Rn = Nt >> 1;
    const int xr = xcd & 3, xcn = xcd >> 2;
    const int Wb = Rn < 8 ? Rn : 8;
    const int cb = idx / (Rm * Wb);
    const int rem = idx - cb * (Rm * Wb);
    mt = xr * Rm + (rem % Rm);
    nt = xcn * Rn + cb * Wb + rem / Rm;
  } else {                                  // Mt%8==0 fallback (odd Nt)
    const int Rm = Mt >> 3;
    const int Wb = Nt < 8 ? Nt : 8;
    const int cb = idx / (Rm * Wb);
    const int rem = idx - cb * (Rm * Wb);
    mt = xcd * Rm + (rem % Rm);
    nt = cb * Wb + rem / Rm;
  }
  const long m0 = (long)mt * 256;
  const long n0 = (long)nt * 256;

  const int nkt = K >> 6;

  // staging source pointers; column pre-swizzled so linear LDS dest holds swizzle
  const int srow = tid >> 2;
  const int scol = ((tid & 3) ^ ((tid >> 3) & 3)) * 8;
  const long arow0 = m0 + srow, arow1 = arow0 + 128;
  long brow0 = n0 + srow, brow1 = brow0 + 128;
  if (brow0 > N - 1) brow0 = N - 1;
  if (brow1 > N - 1) brow1 = N - 1;
  const u16* aS0 = A + arow0 * lda + scol;
  const u16* aS1 = A + arow1 * lda + scol;
  const u16* bS0 = BT + brow0 * (long)K + scol;
  const u16* bS1 = BT + brow1 * (long)K + scol;

  // swizzled fragment-read offsets
  const int aRd = (wr * 128 + lo) * 32 + (hi ^ ((lo >> 1) & 3)) * 8;
  const int bRd = (wc * 64 + lo) * 32 + (hi ^ ((lo >> 1) & 3)) * 8;

  f32x4 acc[8][4] = {};

#define STAGE(s0, s1, koff, dst) do { \
    gload_lds16((s0) + (koff), (dst) + tid * 8); \
    gload_lds16((s1) + (koff), (dst) + 4096 + tid * 8); \
  } while (0)
#define LDA_F(bufr, kh, m) (*(const bf16x8*)(&sA[bufr][kh][aRd + (m) * 512]))
#define LDB_F(bufr, kh, n) (*(const bf16x8*)(&sB[bufr][kh][bRd + (n) * 512]))
#define MFMA_GRP(mi, av) \
    acc[mi][0] = __builtin_amdgcn_mfma_f32_16x16x32_bf16(av, b0, acc[mi][0], 0, 0, 0); \
    acc[mi][1] = __builtin_amdgcn_mfma_f32_16x16x32_bf16(av, b1, acc[mi][1], 0, 0, 0); \
    acc[mi][2] = __builtin_amdgcn_mfma_f32_16x16x32_bf16(av, b2, acc[mi][2], 0, 0, 0); \
    acc[mi][3] = __builtin_amdgcn_mfma_f32_16x16x32_bf16(av, b3, acc[mi][3], 0, 0, 0);

  // prologue: kh0(0) first (forced by the vmcnt8), then kh1(0), kh0(1) (floating 4)
  STAGE(aS0, aS1, 0, &sA[0][0][0]);
  STAGE(bS0, bS1, 0, &sB[0][0][0]);
  STAGE(aS0, aS1, 32, &sA[0][1][0]);
  STAGE(bS0, bS1, 32, &sB[0][1][0]);
  {
    const long t1o = (nkt > 1) ? 64 : 0;
    STAGE(aS0, aS1, t1o, &sA[1][0][0]);
    STAGE(bS0, bS1, t1o, &sB[1][0][0]);
  }
  wait_vm8();
  barrier_raw();

  for (int t = 0; t < nkt; ++t) {
    const int cur = t & 1, nxt = cur ^ 1;
    const int t1c = (t + 1 < nkt) ? t + 1 : nkt - 1;
    const int t2c = (t + 2 < nkt) ? t + 2 : nkt - 1;
    const long o1 = (long)t1c * 64;
    const long o2 = (long)t2c * 64;
    bf16x8 b0, b1, b2, b3, a0, a1, a2, a3, a4, a5, a6, a7;
    // ---- kh0 half: 12 reads pre-barrier; stage A.kh1(t+1); B.kh1(t+1) mid-cluster ----
    b0 = LDB_F(cur, 0, 0); b1 = LDB_F(cur, 0, 1); b2 = LDB_F(cur, 0, 2); b3 = LDB_F(cur, 0, 3);
    a0 = LDA_F(cur, 0, 0); a1 = LDA_F(cur, 0, 1); a2 = LDA_F(cur, 0, 2); a3 = LDA_F(cur, 0, 3);
    a4 = LDA_F(cur, 0, 4); a5 = LDA_F(cur, 0, 5); a6 = LDA_F(cur, 0, 6); a7 = LDA_F(cur, 0, 7);
    STAGE(aS0, aS1, o1 + 32, &sA[nxt][1][0]);
    barrier_raw();
    __builtin_amdgcn_s_setprio(1);
    MFMA_GRP(0, a0) MFMA_GRP(1, a1) MFMA_GRP(2, a2) MFMA_GRP(3, a3)
    __builtin_amdgcn_s_setprio(0);
    STAGE(bS0, bS1, o1 + 32, &sB[nxt][1][0]);
    __builtin_amdgcn_s_setprio(1);
    MFMA_GRP(4, a4) MFMA_GRP(5, a5) MFMA_GRP(6, a6) MFMA_GRP(7, a7)
    __builtin_amdgcn_s_setprio(0);
    wait_vm8();
    barrier_raw();
    // ---- kh1 half: 12 reads; stage A.kh0(t+2); B.kh0(t+2) mid-cluster ----
    b0 = LDB_F(cur, 1, 0); b1 = LDB_F(cur, 1, 1); b2 = LDB_F(cur, 1, 2); b3 = LDB_F(cur, 1, 3);
    a0 = LDA_F(cur, 1, 0); a1 = LDA_F(cur, 1, 1); a2 = LDA_F(cur, 1, 2); a3 = LDA_F(cur, 1, 3);
    a4 = LDA_F(cur, 1, 4); a5 = LDA_F(cur, 1, 5); a6 = LDA_F(cur, 1, 6); a7 = LDA_F(cur, 1, 7);
    STAGE(aS0, aS1, o2, &sA[cur][0][0]);
    barrier_raw();
    __builtin_amdgcn_s_setprio(1);
    MFMA_GRP(0, a0) MFMA_GRP(1, a1) MFMA_GRP(2, a2) MFMA_GRP(3, a3)
    __builtin_amdgcn_s_setprio(0);
    STAGE(bS0, bS1, o2, &sB[cur][0][0]);
    __builtin_amdgcn_s_setprio(1);
    MFMA_GRP(4, a4) MFMA_GRP(5, a5) MFMA_GRP(6, a6) MFMA_GRP(7, a7)
    __builtin_amdgcn_s_setprio(0);
    wait_vm8();
    barrier_raw();
  }
  asm volatile("s_waitcnt vmcnt(0)" ::: "memory");

#undef STAGE
#undef LDA_F
#undef LDB_F
#undef MFMA_GRP

#pragma unroll
  for (int m = 0; m < 8; m++) {
#pragma unroll
    for (int n = 0; n < 4; n++) {
      const long mb = m0 + wr * 128 + m * 16 + hi * 4;
      const long nn = n0 + wc * 64 + n * 16 + lo;
      if (nn >= N) continue;
      const float bv = bias[nn];
      if (MODE == 0) {
#pragma unroll
        for (int r = 0; r < 4; r++)
          ((u16*)outp)[(mb + r) * (long)N + nn] = f2b(acc[m][n][r] + bv);
      } else if (MODE == 3) {
#pragma unroll
        for (int r = 0; r < 4; r++)
          ((float*)outp)[(mb + r) * (long)N + nn] = acc[m][n][r] + bv;
      } else if (MODE == 4) {
        if (nn < 8192) {            // Q_c: (B,NH,L,192) d in [0,128)
          const long h = nn >> 7, d = nn & 127;
#pragma unroll
          for (int r = 0; r < 4; r++) {
            const long mm = mb + r;
            const long bq = mm >> 10, l = mm & 1023;
            ((u16*)outp)[((bq * 64 + h) * 1024 + l) * 192 + d] = f2b(acc[m][n][r] + bv);
          }
        } else {                    // Q_r: d in [128,192)
          const long q = nn - 8192;
          const long h = q >> 6, d = q & 63;
#pragma unroll
          for (int r = 0; r < 4; r++) {
            const long mm = mb + r;
            const long bq = mm >> 10, l = mm & 1023;
            ((u16*)outp)[((bq * 64 + h) * 1024 + l) * 192 + 128 + d] = f2b(acc[m][n][r] + bv);
          }
        }
      } else {                      // MODE 5
        if (nn < 8192) {            // K_c into Kbuf (outp)
          const long h = nn >> 7, d = nn & 127;
#pragma unroll
          for (int r = 0; r < 4; r++) {
            const long mm = mb + r;
            const long bq = mm >> 10, l = mm & 1023;
            ((u16*)outp)[((bq * 64 + h) * 1024 + l) * 192 + d] = f2b(acc[m][n][r] + bv);
          }
        } else {                    // V into Vt (outp2), transposed (B,NH,128,L)
          const long v = nn - 8192;
          const long h = v >> 7, d = v & 127;
          u16x4 pk;
#pragma unroll
          for (int r = 0; r < 4; r++) pk[r] = f2b(acc[m][n][r] + bv);
          const long bq = mb >> 10, l = mb & 1023;
          *(u16x4*)((u16*)outp2 + ((bq * 64 + h) * 128 + d) * 1024 + l) = pk;
        }
      }
    }
  }
}

// ---------------- causal flash attention, 8-wave 256-row q-tile, LDS-staged K/V ----------------
__global__ __launch_bounds__(512, 2) void attn256(const u16* __restrict__ Qb,
                                                  const u16* __restrict__ Kb,
                                                  const u16* __restrict__ Vt,
                                                  u16* __restrict__ O) {
  __shared__ u16 sK[2][12288];   // 64 keys x 192 dims, 24 chunks/row
  __shared__ u16 sV[2][8192];    // 128 d x 64 keys, 8 chunks/row
  __shared__ u16 P[8][32][72];   // per-wave P tiles (2 qi x 16 rows)
  const int bh = blockIdx.x;
  const int qtb = 3 - blockIdx.y;            // longest blocks dispatch first
  const int b = bh >> 6, h = bh & 63;
  const int tid = threadIdx.x, w = tid >> 6, lane = tid & 63;
  const int hi = lane >> 4, lo = lane & 15, lo7 = lane & 7;
  const int q0w = qtb * 256 + w * 32;
  const u16* Qh = Qb + (size_t)bh * 1024 * 192;
  const u16* Kh = Kb + (size_t)bh * 1024 * 192;
  const u16* Vh = Vt + (size_t)bh * 128 * 1024;
  const float scale = 0.08838834764831845f;  // 1/sqrt(128)
  const float NEGINF = -3.0e38f;

  int kOff0, kOff1, kOff2, vOff0, vOff1;
  {
    int g0 = tid, g1 = tid + 512, g2 = tid + 1024;
    int r0 = g0 / 24, r1 = g1 / 24, r2 = g2 / 24;
    kOff0 = r0 * 192 + ((g0 - r0 * 24) ^ (r0 & 7)) * 8;
    kOff1 = r1 * 192 + ((g1 - r1 * 24) ^ (r1 & 7)) * 8;
    kOff2 = r2 * 192 + ((g2 - r2 * 24) ^ (r2 & 7)) * 8;
    int s0 = tid, s1 = tid + 512;
    vOff0 = (s0 >> 3) * 1024 + ((s0 & 7) ^ ((s0 >> 3) & 7)) * 8;
    vOff1 = (s1 >> 3) * 1024 + ((s1 & 7) ^ ((s1 >> 3) & 7)) * 8;
  }
#define STAGE_KV(tt, bb) do { \
    const u16* kb_ = Kh + (size_t)(tt) * (64 * 192); \
    const u16* vb_ = Vh + (size_t)(tt) * 64; \
    gload_lds16(kb_ + kOff0, &sK[bb][0] + tid * 8); \
    gload_lds16(kb_ + kOff1, &sK[bb][4096] + tid * 8); \
    gload_lds16(kb_ + kOff2, &sK[bb][8192] + tid * 8); \
    gload_lds16(vb_ + vOff0, &sV[bb][0] + tid * 8); \
    gload_lds16(vb_ + vOff1, &sV[bb][4096] + tid * 8); \
  } while (0)

  bf16x8 qf[2][6];
#pragma unroll
  for (int qi = 0; qi < 2; qi++) {
    const u16* qp = Qh + (size_t)(q0w + qi * 16 + lo) * 192 + hi * 8;
#pragma unroll
    for (int f = 0; f < 6; f++) qf[qi][f] = *(const bf16x8*)(qp + f * 32);
  }

  f32x4 oacc[2][8] = {};
  float m_run[2][4], l_run[2][4];
#pragma unroll
  for (int qi = 0; qi < 2; qi++)
#pragma unroll
    for (int r = 0; r < 4; r++) { m_run[qi][r] = NEGINF; l_run[qi][r] = 0.f; }

  const int nkt = (qtb + 1) * 4;
  STAGE_KV(0, 0);
  __syncthreads();

  for (int t = 0; t < nkt; t++) {
    const int cur = t & 1;
    const int tn = (t + 1 < nkt) ? t + 1 : nkt - 1;
    STAGE_KV(tn, cur ^ 1);
    const int k0 = t * 64;
    if (k0 < q0w + 32) {
      f32x4 s[2][4] = {};
      __builtin_amdgcn_s_setprio(1);
#pragma unroll
      for (int j = 0; j < 4; j++) {
#pragma unroll
        for (int f = 0; f < 6; f++) {
          bf16x8 kf = *(const bf16x8*)(&sK[cur][((j * 16 + lo) * 24 + ((f * 4 + hi) ^ lo7)) * 8]);
          s[0][j] = __builtin_amdgcn_mfma_f32_16x16x32_bf16(qf[0][f], kf, s[0][j], 0, 0, 0);
          s[1][j] = __builtin_amdgcn_mfma_f32_16x16x32_bf16(qf[1][f], kf, s[1][j], 0, 0, 0);
        }
      }
      __builtin_amdgcn_s_setprio(0);
      const bool diag = (k0 + 63 > q0w);
#pragma unroll
      for (int qi = 0; qi < 2; qi++) {
#pragma unroll
        for (int r = 0; r < 4; r++) {
          const int q = q0w + qi * 16 + hi * 4 + r;
          float sv[4];
          float mx = NEGINF;
#pragma unroll
          for (int j = 0; j < 4; j++) {
            float v = s[qi][j][r] * scale;
            if (diag && (k0 + j * 16 + lo > q)) v = NEGINF;
            sv[j] = v;
            mx = fmaxf(mx, v);
          }
#pragma unroll
          for (int o = 1; o < 16; o <<= 1) mx = fmaxf(mx, __shfl_xor(mx, o, 64));
          const float mnew = fmaxf(m_run[qi][r], mx);
          float sum = 0.f;
#pragma unroll
          for (int j = 0; j < 4; j++) {
            float pv = __expf(sv[j] - mnew);
            sum += pv;
            P[w][qi * 16 + hi * 4 + r][j * 16 + lo] = f2b(pv);
          }
#pragma unroll
          for (int o = 1; o < 16; o <<= 1) sum += __shfl_xor(sum, o, 64);
          const float alpha = __expf(m_run[qi][r] - mnew);
          l_run[qi][r] = l_run[qi][r] * alpha + sum;
          m_run[qi][r] = mnew;
#pragma unroll
          for (int j = 0; j < 8; j++) oacc[qi][j][r] *= alpha;
        }
      }
      __builtin_amdgcn_s_setprio(1);
#pragma unroll
      for (int kk = 0; kk < 2; kk++) {
        bf16x8 pf0 = *(const bf16x8*)(&P[w][lo][kk * 32 + hi * 8]);
        bf16x8 pf1 = *(const bf16x8*)(&P[w][16 + lo][kk * 32 + hi * 8]);
#pragma unroll
        for (int j = 0; j < 8; j++) {
          bf16x8 vf = *(const bf16x8*)(&sV[cur][((j * 16 + lo) * 8 + ((kk * 4 + hi) ^ lo7)) * 8]);
          oacc[0][j] = __builtin_amdgcn_mfma_f32_16x16x32_bf16(pf0, vf, oacc[0][j], 0, 0, 0);
          oacc[1][j] = __builtin_amdgcn_mfma_f32_16x16x32_bf16(pf1, vf, oacc[1][j], 0, 0, 0);
        }
      }
      __builtin_amdgcn_s_setprio(0);
    }
    __syncthreads();
  }
#undef STAGE_KV

#pragma unroll
  for (int qi = 0; qi < 2; qi++) {
#pragma unroll
    for (int r = 0; r < 4; r++) {
      const float inv = 1.f / l_run[qi][r];
      const int q = q0w + qi * 16 + hi * 4 + r;
      u16* op = O + ((size_t)(b * 1024 + q) * 64 + h) * 128;
#pragma unroll
      for (int j = 0; j < 8; j++)
        op[j * 16 + lo] = f2b(oacc[qi][j][r] * inv);
    }
  }
}

// ---------------- launcher ----------------
extern "C" void kernel_launch(void* const* d_in, const int* in_sizes, int n_in,
                              void* d_out, int out_size, void* d_ws, size_t ws_size,
                              hipStream_t stream) {
  const float* x     = (const float*)d_in[0];
  const float* W_dq  = (const float*)d_in[1];
  const float* b_dq  = (const float*)d_in[2];
  const float* W_dkv = (const float*)d_in[3];
  const float* b_dkv = (const float*)d_in[4];
  const float* W_uq  = (const float*)d_in[5];
  const float* b_uq  = (const float*)d_in[6];
  const float* W_uk  = (const float*)d_in[7];
  const float* b_uk  = (const float*)d_in[8];
  const float* W_uv  = (const float*)d_in[9];
  const float* b_uv  = (const float*)d_in[10];
  const float* W_pq  = (const float*)d_in[11];
  const float* b_pq  = (const float*)d_in[12];
  const float* W_pk  = (const float*)d_in[13];
  const float* b_pk  = (const float*)d_in[14];
  const float* W_o   = (const float*)d_in[15];
  const float* b_o   = (const float*)d_in[16];

  char* ws = (char*)d_ws;
  size_t off = 0;
  auto alloc = [&](size_t bytes) {
    char* p = ws + off;
    off += (bytes + 255) & ~(size_t)255;
    return p;
  };
  u16* xbf   = (u16*)alloc(33554432ULL * 2);   // x bf16; reused as attn O
  u16* WT    = (u16*)alloc(67108864ULL * 2);   // transposed-weight scratch (max = W_o)
  u16* lat   = (u16*)alloc(4096ULL * 2112 * 2);// [Q_lat | KV_lat | K_r]
  float* bct = (float*)alloc(2112ULL * 4);
  float* bq  = (float*)alloc(12288ULL * 4);
  float* bkv = (float*)alloc(16384ULL * 4);
  u16* Qbuf  = (u16*)alloc(100663296ULL);      // (B,NH,L,192)
  u16* Kbuf  = (u16*)alloc(100663296ULL);      // (B,NH,L,192)
  u16* Vt    = (u16*)alloc(67108864ULL);       // (B,NH,128,L)
  u16* Obuf  = xbf;
  if (off > ws_size) return;

  dim3 blk(256), blk5(512);
  cvt_bf16<<<dim3(32768), blk, 0, stream>>>(x, xbf, 33554432L);
  // fused latent: [Q_lat | KV_lat | K_r] = x @ [W_dq | W_dkv | W_pk] + biases
  transpose_cvt<<<dim3(48, 256), blk, 0, stream>>>(W_dq, WT, 8192, 1536);
  transpose_cvt<<<dim3(16, 256), blk, 0, stream>>>(W_dkv, WT + 1536L * 8192, 8192, 512);
  transpose_cvt<<<dim3(2, 256), blk, 0, stream>>>(W_pk, WT + 2048L * 8192, 8192, 64);
  biascat3<<<dim3(9), blk, 0, stream>>>(b_dq, b_dkv, b_pk, bct);
  gemm256<0><<<dim3(9, 16), blk5, 0, stream>>>(xbf, 8192, WT, bct, lat, nullptr, 2112, 8192);
  repl_kr<<<dim3(16384), blk, 0, stream>>>(lat + 2048, Kbuf, 2112);
  // fused Q: [Q_c | Q_r] = Q_lat @ [W_uq | W_pq], N = 12288
  transpose_cvt<<<dim3(256, 48), blk, 0, stream>>>(W_uq, WT, 1536, 8192);
  transpose_cvt<<<dim3(128, 48), blk, 0, stream>>>(W_pq, WT + 8192L * 1536, 1536, 4096);
  biascat2<<<dim3(48), blk, 0, stream>>>(b_uq, b_pq, 8192, 12288, bq);
  gemm256<4><<<dim3(48, 16), blk5, 0, stream>>>(lat, 2112, WT, bq, Qbuf, nullptr, 12288, 1536);
  // fused KV: [K_c | V] = KV_lat @ [W_uk | W_uv], N = 16384
  transpose_cvt<<<dim3(256, 16), blk, 0, stream>>>(W_uk, WT, 512, 8192);
  transpose_cvt<<<dim3(256, 16), blk, 0, stream>>>(W_uv, WT + 8192L * 512, 512, 8192);
  biascat2<<<dim3(64), blk, 0, stream>>>(b_uk, b_uv, 8192, 16384, bkv);
  gemm256<5><<<dim3(64, 16), blk5, 0, stream>>>(lat + 1536, 2112, WT, bkv, Kbuf, Vt, 16384, 512);
  // attention (8-wave, 256-row q-tiles, LDS-staged K/V)
  attn256<<<dim3(256, 4), blk5, 0, stream>>>(Qbuf, Kbuf, Vt, Obuf);
  // out = O @ W_o + b_o (fp32)
  transpose_cvt<<<dim3(256, 256), blk, 0, stream>>>(W_o, WT, 8192, 8192);
  gemm256<3><<<dim3(32, 16), blk5, 0, stream>>>(Obuf, 8192, WT, b_o, d_out, nullptr, 8192, 8192);
}